// Round 9
// baseline (293.274 us; speedup 1.0000x reference)
//
#include <hip/hip_runtime.h>

// B=16, Q=2048, K=2048, D=128, DV=128
// out[b,q,:] = softmax_k((q.k - 0.5||k||^2)/sqrt(192), mask k>=valid_len) @ V
// R9: split-K x2 (grid 1024: b x 32 q-slots x 2 key-halves), single-buffered
// K/V tiles (33.5KB LDS) with raw vmcnt(0)+s_barrier staging -> 4 blocks/CU,
// 16 waves/CU (was 8). Blocks write unnormalized partials (bf16 O, f32 l) to
// ws; second finisher block of each pair (same-XCD partner lin^8, acq_rel
// atomic flag) merges + normalizes. Core S/softmax/PV identical to R8.

#define Bn   16
#define Qn   2048
#define Kn   2048
#define Dn   128
#define DVn  128
#define BQ   64
#define BK   64

// (1/sqrt(192)) * log2(e) : softmax computed as 2^(qk*SC2 + bias2)
#define SC2 0.10411754f

typedef short bf16x4 __attribute__((ext_vector_type(4)));
typedef short bf16x8 __attribute__((ext_vector_type(8)));
typedef float f32x16 __attribute__((ext_vector_type(16)));

__device__ __forceinline__ short f2bf(float x) {   // RNE
    union { float f; unsigned u; } v; v.f = x;
    unsigned r = (v.u + 0x7fffu + ((v.u >> 16) & 1u)) >> 16;
    return (short)r;
}
__device__ __forceinline__ float bf2f(short s) {
    return __uint_as_float(((unsigned)(unsigned short)s) << 16);
}

typedef const __attribute__((address_space(1))) void* gas_t;
typedef __attribute__((address_space(3))) void* las_t;
__device__ __forceinline__ void gld16(const void* g, void* l) {
    __builtin_amdgcn_global_load_lds((gas_t)g, (las_t)l, 16, 0, 0);
}
__device__ __forceinline__ void gld4(const void* g, void* l) {
    __builtin_amdgcn_global_load_lds((gas_t)g, (las_t)l, 4, 0, 0);
}
__device__ __forceinline__ void barrier_lgkm() {
    asm volatile("s_waitcnt lgkmcnt(0)" ::: "memory");
    __builtin_amdgcn_s_barrier();
    asm volatile("" ::: "memory");
}
__device__ __forceinline__ void barrier_vm() {
    asm volatile("s_waitcnt vmcnt(0)" ::: "memory");
    __builtin_amdgcn_s_barrier();
    asm volatile("" ::: "memory");
}
__device__ __forceinline__ float exp2_raw(float a) {  // D = 2^S0
    float p;
    asm("v_exp_f32 %0, %1" : "=v"(p) : "v"(a));
    return p;
}

// ---------- preprocess (identical to R4..R8) ----------
__global__ __launch_bounds__(256) void prep_kv(const float* __restrict__ Kg,
                                               const float* __restrict__ Vg,
                                               short* __restrict__ Kb,
                                               short* __restrict__ Vtb,
                                               float* __restrict__ biasg) {
    __shared__ short Ls[64 * 128];
    const int tid = threadIdx.x;
    if (blockIdx.x < 512) {
        const int b  = blockIdx.x >> 5;
        const int k0 = (blockIdx.x & 31) * 64;
        const int row = k0 + (tid >> 2);
        const int c   = (tid & 3) * 32;
        const float* src = Kg + ((size_t)b * Kn + row) * Dn + c;
        short*       dst = Kb + ((size_t)b * Kn + row) * Dn + c;
        float ssq = 0.f;
#pragma unroll
        for (int j = 0; j < 4; ++j) {
            float4 x0 = *(const float4*)(src + j * 8);
            float4 x1 = *(const float4*)(src + j * 8 + 4);
            ssq += x0.x*x0.x + x0.y*x0.y + x0.z*x0.z + x0.w*x0.w
                 + x1.x*x1.x + x1.y*x1.y + x1.z*x1.z + x1.w*x1.w;
            bf16x8 h;
            h[0]=f2bf(x0.x); h[1]=f2bf(x0.y); h[2]=f2bf(x0.z); h[3]=f2bf(x0.w);
            h[4]=f2bf(x1.x); h[5]=f2bf(x1.y); h[6]=f2bf(x1.z); h[7]=f2bf(x1.w);
            *(bf16x8*)(dst + j * 8) = h;
        }
        ssq += __shfl_xor(ssq, 1);
        ssq += __shfl_xor(ssq, 2);
        if ((tid & 3) == 0) biasg[b * Kn + row] = -0.5f * ssq * SC2;
    } else {
        const int blk = blockIdx.x - 512;
        const int b  = blk >> 5;
        const int k0 = (blk & 31) * 64;
        {
            const int key = tid >> 2;
            const float* src = Vg + ((size_t)b * Kn + k0 + key) * DVn + (tid & 3) * 32;
#pragma unroll
            for (int cj = 0; cj < 4; ++cj) {
                float4 x0 = *(const float4*)(src + cj * 8);
                float4 x1 = *(const float4*)(src + cj * 8 + 4);
                bf16x8 h;
                h[0]=f2bf(x0.x); h[1]=f2bf(x0.y); h[2]=f2bf(x0.z); h[3]=f2bf(x0.w);
                h[4]=f2bf(x1.x); h[5]=f2bf(x1.y); h[6]=f2bf(x1.z); h[7]=f2bf(x1.w);
                const int ch = (tid & 3) * 4 + cj;
                const int sw = (ch + key) & 15;
                *(bf16x8*)&Ls[key * 128 + sw * 8] = h;
            }
        }
        __syncthreads();
        {
            const int v = tid >> 1;
            const int h = (tid & 1) * 32;
            short tmp[32];
#pragma unroll
            for (int j = 0; j < 32; ++j) {
                const int kk = h + j;
                const int sw = ((v >> 3) + kk) & 15;
                tmp[j] = Ls[kk * 128 + sw * 8 + (v & 7)];
            }
            short* dst = Vtb + ((size_t)b * DVn + v) * Kn + k0 + h;
#pragma unroll
            for (int j = 0; j < 4; ++j)
                *(bf16x8*)(dst + j * 8) = *(bf16x8*)(tmp + j * 8);
        }
    }
}

// epilogue helpers with LITERAL accumulator indices (no runtime Oacc[] index)
#define DUMP_ACC(ACC, DST)                                            \
    {                                                                 \
        _Pragma("unroll")                                             \
        for (int reg = 0; reg < 16; ++reg) {                          \
            const int row = (reg & 3) + 8 * (reg >> 2) + 4 * hi;      \
            (DST)[row * 32 + l31] = (ACC)[reg];                       \
        }                                                             \
    }
#define PSTORE_ACC(ACC, SRC, COLBASE)                                 \
    {                                                                 \
        _Pragma("unroll")                                             \
        for (int reg = 0; reg < 16; ++reg) {                          \
            const int row = (reg & 3) + 8 * (reg >> 2) + 4 * hi;      \
            const float o = (ACC)[reg] + (SRC)[row * 32 + l31];       \
            op[(size_t)(pair * 32 + row) * 128 + (COLBASE) + l31] = f2bf(o); \
        }                                                             \
    }

// ---------- main attention kernel (split-K x2) ----------
__global__ __launch_bounds__(256, 4) void attn_kernel(
    const float* __restrict__ Qg, const short* __restrict__ Kb,
    const short* __restrict__ Vtb, const float* __restrict__ biasg,
    const int* __restrict__ VL,
    short* __restrict__ Opart, float* __restrict__ Lpart,
    unsigned* __restrict__ flags, float* __restrict__ Og)
{
    // Single-buffered tiles: K at KVsh[0..8192), V at KVsh[8192..16384)
    // K tile: 64 rows x 256B, chunk XOR by (row&15)
    // V tile: 64 rows x 256B; row r holds v=2r (slots c<8) / v=2r+1 (c>=8),
    //         slot position p = c ^ (r&15)
    __shared__ __align__(16) short KVsh[2 * 64 * 128];   // 32768 B (epilogue: float slab)
    __shared__ __align__(16) float biasSh[64];           //   256 B
    __shared__ float Lsum[4][32];                        //   512 B
    __shared__ unsigned role;                            // -> ~33.6 KB total

    const int tid  = threadIdx.x;
    const int lane = tid & 63;
    const int w    = tid >> 6;    // wave 0..3
    const int pair = w >> 1;      // q-strip: rows [pair*32, pair*32+32)
    const int half = w & 1;       // key-half within the 64-key tile (wave-uniform)
    const int l31  = lane & 31;
    const int hi   = lane >> 5;

    // grid 1024: bits 0-2 = XCD, bit 3 = khalf, bits 4-9 = rest
    const int lin   = blockIdx.x;
    const int xcd   = lin & 7;
    const int g     = lin >> 3;            // 0..127
    const int b     = xcd * 2 + (g >> 6);  // 2 batches per XCD
    const int rem   = g & 63;
    const int qslot = rem >> 1;            // 0..31
    const int khalf = rem & 1;
    const int q0    = qslot * BQ;
    const int kbase = khalf * (Kn / 2);    // 16 tiles of 64 keys
    const int fidx  = ((lin >> 4) << 3) | (lin & 7);   // 0..511 per (b,qslot)

    const short* Kb_b = Kb  + (size_t)b * Kn * Dn;
    const short* Vt_b = Vtb + (size_t)b * DVn * Kn;
    const float* bias_b = biasg + b * Kn;

    short* Ksh = &KVsh[0];
    short* Vsh = &KVsh[64 * 128];

    // ---- DMA source pointers ----
    const short* ksp[4]; int kdo[4];
    const short* vsp[4]; int vdo[4];
#pragma unroll
    for (int i = 0; i < 4; ++i) {
        const int rl = w * 16 + i * 4 + (lane >> 4);       // K tile row 0..63
        const int ch = (lane & 15) ^ (rl & 15);
        ksp[i] = Kb_b + (size_t)rl * Dn + ch * 8;
        kdo[i] = (w * 16 + i * 4) * 128;
        const int rv = w * 16 + i * 4 + (lane >> 4);       // V tile row 0..63
        const int cc = (lane & 15) ^ (rv & 15);            // source chunk
        const int vv = 2 * rv + (cc >> 3);
        vsp[i] = Vt_b + (size_t)vv * Kn + (cc & 7) * 8;
        vdo[i] = (w * 16 + i * 4) * 128;
    }

    // ---- Q fragments: frag layout [n=l31][k=kt*16+hi*8+j] ----
    bf16x8 qf[8];
    {
        const float* qrow = Qg + ((size_t)b * Qn + q0 + pair * 32 + l31) * Dn;
#pragma unroll
        for (int kt = 0; kt < 8; ++kt) {
            const float* p = qrow + kt * 16 + hi * 8;
            float4 x0 = *(const float4*)(p);
            float4 x1 = *(const float4*)(p + 4);
            bf16x8 f;
            f[0]=f2bf(x0.x); f[1]=f2bf(x0.y); f[2]=f2bf(x0.z); f[3]=f2bf(x0.w);
            f[4]=f2bf(x1.x); f[5]=f2bf(x1.y); f[6]=f2bf(x1.z); f[7]=f2bf(x1.w);
            qf[kt] = f;
        }
    }
    const int vlq = VL[b * Qn + q0 + pair * 32 + l31];

    f32x16 Oacc[4];   // v = nt*32 + l31, all 128 v; keys restricted to own half
#pragma unroll
    for (int nt = 0; nt < 4; ++nt)
#pragma unroll
        for (int j = 0; j < 16; ++j) Oacc[nt][j] = 0.f;
    float psum = 0.f;

    for (int t = 0; t < 16; ++t) {
        const int k0k = kbase + t * BK;

        // ---- issue DMA for tile t into the single buffer ----
#pragma unroll
        for (int i = 0; i < 4; ++i) {
            gld16(ksp[i] + (size_t)k0k * Dn, &Ksh[kdo[i]]);
            gld16(vsp[i] + k0k,              &Vsh[vdo[i]]);
        }
        if (w == 0) gld4(bias_b + k0k + lane, &biasSh[0]);
        barrier_vm();   // tile ready (prev readers done at loop-end barrier)

        float4 bv[4];
#pragma unroll
        for (int rq = 0; rq < 4; ++rq)
            bv[rq] = *(const float4*)&biasSh[half * 32 + rq * 8 + hi * 4];

        // ---- S^T = K_half . Q^T : one 32x32 tile per wave (8 MFMA) ----
        const int kr = half * 32 + l31;
        f32x16 Sv;
#pragma unroll
        for (int j = 0; j < 16; ++j) Sv[j] = 0.f;
#pragma unroll
        for (int kt = 0; kt < 8; ++kt) {
            bf16x8 kf = *(const bf16x8*)&Ksh[kr * 128 + (((kt*2 + hi) ^ (kr & 15)) * 8)];
            Sv = __builtin_amdgcn_mfma_f32_32x32x16_bf16(kf, qf[kt], Sv, 0, 0, 0);
        }

        // ---- softmax in exp2 domain (results back into Sv) ----
#pragma unroll
        for (int rq = 0; rq < 4; ++rq) {
#pragma unroll
            for (int r = 0; r < 4; ++r) {
                const int reg = rq * 4 + r;
                const int keyg = k0k + half * 32 + rq * 8 + hi * 4 + r;
                float a = fmaf(Sv[reg], SC2, bv[rq][r]);
                a = (keyg < vlq) ? a : -200.0f;
                const float p = exp2_raw(a);
                psum += p;
                Sv[reg] = p;
            }
        }

        // ---- PV: C-layout -> A-layout via lane^32 exchange; 8 MFMA ----
#pragma unroll
        for (int kt = 0; kt < 2; ++kt) {
            unsigned kAx = __builtin_amdgcn_perm(__float_as_uint(Sv[(2*kt)*4+1]),
                                                 __float_as_uint(Sv[(2*kt)*4+0]), 0x07060302u);
            unsigned kAy = __builtin_amdgcn_perm(__float_as_uint(Sv[(2*kt)*4+3]),
                                                 __float_as_uint(Sv[(2*kt)*4+2]), 0x07060302u);
            unsigned kBx = __builtin_amdgcn_perm(__float_as_uint(Sv[(2*kt+1)*4+1]),
                                                 __float_as_uint(Sv[(2*kt+1)*4+0]), 0x07060302u);
            unsigned kBy = __builtin_amdgcn_perm(__float_as_uint(Sv[(2*kt+1)*4+3]),
                                                 __float_as_uint(Sv[(2*kt+1)*4+2]), 0x07060302u);
            const unsigned sx = hi ? kAx : kBx;
            const unsigned sy = hi ? kAy : kBy;
            const unsigned rx = __shfl_xor(sx, 32);
            const unsigned ry = __shfl_xor(sy, 32);
            uint4 au;
            au.x = hi ? rx : kAx;
            au.y = hi ? ry : kAy;
            au.z = hi ? kBx : rx;
            au.w = hi ? kBy : ry;
            const bf16x8 af = __builtin_bit_cast(bf16x8, au);
            const int kc = half * 4 + kt * 2 + hi;   // key-chunk within 64-key tile
#pragma unroll
            for (int nt = 0; nt < 4; ++nt) {
                const int v  = nt * 32 + l31;
                const int r  = v >> 1;
                const int p  = ((v & 1) * 8 + kc) ^ (r & 15);
                bf16x8 vf = *(const bf16x8*)&Vsh[r * 128 + p * 8];
                Oacc[nt] = __builtin_amdgcn_mfma_f32_32x32x16_bf16(af, vf, Oacc[nt], 0, 0, 0);
            }
        }

        barrier_lgkm();   // readers done -> next iter may overwrite the buffer
    }

    // ---- epilogue: merge key-halves within block, write partials to ws ----
    psum += __shfl_xor(psum, 32);
    if (lane < 32) Lsum[w][l31] = psum;
    __syncthreads();   // all waves done with KVsh -> reuse as float slab

    float* slab = (float*)&KVsh[0];
    {
        float* dst0 = slab + ((pair * 2 + (1 - half)) * 2 + 0) * 1024;
        float* dst1 = slab + ((pair * 2 + (1 - half)) * 2 + 1) * 1024;
        if (half == 0) {
            DUMP_ACC(Oacc[2], dst0);
            DUMP_ACC(Oacc[3], dst1);
        } else {
            DUMP_ACC(Oacc[0], dst0);
            DUMP_ACC(Oacc[1], dst1);
        }
    }
    __syncthreads();

    // per-row partial l (sum over both key-halves of this block's K-range)
    if (l31 == 0 && half == 0) {
#pragma unroll
        for (int reg = 0; reg < 16; ++reg) {
            const int ql = (reg & 3) + 8 * (reg >> 2) + 4 * hi;
            Lpart[lin * 64 + pair * 32 + ql] = Lsum[pair*2][ql] + Lsum[pair*2+1][ql];
        }
    }

    short* op = Opart + (size_t)lin * 64 * 128;
    {
        const float* src0 = slab + ((pair * 2 + half) * 2 + 0) * 1024;
        const float* src1 = slab + ((pair * 2 + half) * 2 + 1) * 1024;
        if (half == 0) {
            PSTORE_ACC(Oacc[0], src0, 0);
            PSTORE_ACC(Oacc[1], src1, 32);
        } else {
            PSTORE_ACC(Oacc[2], src0, 64);
            PSTORE_ACC(Oacc[3], src1, 96);
        }
    }

    // ---- finisher protocol: second block of the (b,qslot) pair merges ----
    __syncthreads();   // all partial stores issued before the release atomic
    if (tid == 0) {
        __threadfence();
        role = __hip_atomic_fetch_add(&flags[fidx], 1u,
                                      __ATOMIC_ACQ_REL, __HIP_MEMORY_SCOPE_AGENT);
    }
    __syncthreads();
    if (role == 1) {
        const size_t pA = (size_t)(lin & ~8) * 64 * 128;
        const size_t pB = (size_t)(lin |  8) * 64 * 128;
        const int lA = (lin & ~8) * 64;
        const int lB = (lin |  8) * 64;
        const int col   = tid & 127;
        const int rbase = (tid >> 7) * 32;
        float* og = Og + ((size_t)b * Qn + q0) * DVn;
        for (int i = 0; i < 32; ++i) {
            const int row = rbase + i;
            const float o = bf2f(Opart[pA + row * 128 + col])
                          + bf2f(Opart[pB + row * 128 + col]);
            const float l = Lpart[lA + row] + Lpart[lB + row];
            og[(size_t)row * DVn + col] = o / l;
        }
    }
}

extern "C" void kernel_launch(void* const* d_in, const int* in_sizes, int n_in,
                              void* d_out, int out_size, void* d_ws, size_t ws_size,
                              hipStream_t stream) {
    const float* Qg = (const float*)d_in[0];
    const float* Kg = (const float*)d_in[1];
    const float* Vg = (const float*)d_in[2];
    const int*   VL = (const int*)d_in[3];
    float* Og = (float*)d_out;

    // ws: Kb bf16 8MB | Vtb bf16 8MB | bias2 f32 128KB | Opart bf16 16MB |
    //     Lpart f32 256KB | flags 2KB   (total ~32.4MB)
    char* ws = (char*)d_ws;
    short*    Kb    = (short*)(ws);
    short*    Vtb   = (short*)(ws + 8388608);
    float*    bias  = (float*)(ws + 16777216);
    short*    Opart = (short*)(ws + 16908288);
    float*    Lpart = (float*)(ws + 33685504);
    unsigned* flags = (unsigned*)(ws + 33947648);

    hipMemsetAsync(flags, 0, 512 * sizeof(unsigned), stream);
    prep_kv<<<dim3(1024), dim3(256), 0, stream>>>(Kg, Vg, Kb, Vtb, bias);
    attn_kernel<<<dim3(1024), dim3(256), 0, stream>>>(Qg, Kb, Vtb, bias, VL,
                                                      Opart, Lpart, flags, Og);
}

// Round 10
// 239.282 us; speedup vs baseline: 1.2256x; 1.2256x over previous
//
#include <hip/hip_runtime.h>

// B=16, Q=2048, K=2048, D=128, DV=128
// out[b,q,:] = softmax_k((q.k - 0.5||k||^2)/sqrt(192), mask k>=valid_len) @ V
// R10 = R9 with launch_bounds fixed (256,4)->(256,3): R9's bound forced a
// 64-VGPR cap -> total accumulator spill (FETCH 342MB). Cap ~168 VGPRs keeps
// the kernel spill-free (~96-128 natural) while 33.8KB LDS still allows
// 4 blocks/CU. Split-K x2 + single-buffered tiles + finisher unchanged.

#define Bn   16
#define Qn   2048
#define Kn   2048
#define Dn   128
#define DVn  128
#define BQ   64
#define BK   64

// (1/sqrt(192)) * log2(e) : softmax computed as 2^(qk*SC2 + bias2)
#define SC2 0.10411754f

typedef short bf16x4 __attribute__((ext_vector_type(4)));
typedef short bf16x8 __attribute__((ext_vector_type(8)));
typedef float f32x16 __attribute__((ext_vector_type(16)));

__device__ __forceinline__ short f2bf(float x) {   // RNE
    union { float f; unsigned u; } v; v.f = x;
    unsigned r = (v.u + 0x7fffu + ((v.u >> 16) & 1u)) >> 16;
    return (short)r;
}
__device__ __forceinline__ float bf2f(short s) {
    return __uint_as_float(((unsigned)(unsigned short)s) << 16);
}

typedef const __attribute__((address_space(1))) void* gas_t;
typedef __attribute__((address_space(3))) void* las_t;
__device__ __forceinline__ void gld16(const void* g, void* l) {
    __builtin_amdgcn_global_load_lds((gas_t)g, (las_t)l, 16, 0, 0);
}
__device__ __forceinline__ void gld4(const void* g, void* l) {
    __builtin_amdgcn_global_load_lds((gas_t)g, (las_t)l, 4, 0, 0);
}
__device__ __forceinline__ void barrier_lgkm() {
    asm volatile("s_waitcnt lgkmcnt(0)" ::: "memory");
    __builtin_amdgcn_s_barrier();
    asm volatile("" ::: "memory");
}
__device__ __forceinline__ void barrier_vm() {
    asm volatile("s_waitcnt vmcnt(0)" ::: "memory");
    __builtin_amdgcn_s_barrier();
    asm volatile("" ::: "memory");
}
__device__ __forceinline__ float exp2_raw(float a) {  // D = 2^S0
    float p;
    asm("v_exp_f32 %0, %1" : "=v"(p) : "v"(a));
    return p;
}

// ---------- preprocess (identical to R4..R9) ----------
__global__ __launch_bounds__(256) void prep_kv(const float* __restrict__ Kg,
                                               const float* __restrict__ Vg,
                                               short* __restrict__ Kb,
                                               short* __restrict__ Vtb,
                                               float* __restrict__ biasg) {
    __shared__ short Ls[64 * 128];
    const int tid = threadIdx.x;
    if (blockIdx.x < 512) {
        const int b  = blockIdx.x >> 5;
        const int k0 = (blockIdx.x & 31) * 64;
        const int row = k0 + (tid >> 2);
        const int c   = (tid & 3) * 32;
        const float* src = Kg + ((size_t)b * Kn + row) * Dn + c;
        short*       dst = Kb + ((size_t)b * Kn + row) * Dn + c;
        float ssq = 0.f;
#pragma unroll
        for (int j = 0; j < 4; ++j) {
            float4 x0 = *(const float4*)(src + j * 8);
            float4 x1 = *(const float4*)(src + j * 8 + 4);
            ssq += x0.x*x0.x + x0.y*x0.y + x0.z*x0.z + x0.w*x0.w
                 + x1.x*x1.x + x1.y*x1.y + x1.z*x1.z + x1.w*x1.w;
            bf16x8 h;
            h[0]=f2bf(x0.x); h[1]=f2bf(x0.y); h[2]=f2bf(x0.z); h[3]=f2bf(x0.w);
            h[4]=f2bf(x1.x); h[5]=f2bf(x1.y); h[6]=f2bf(x1.z); h[7]=f2bf(x1.w);
            *(bf16x8*)(dst + j * 8) = h;
        }
        ssq += __shfl_xor(ssq, 1);
        ssq += __shfl_xor(ssq, 2);
        if ((tid & 3) == 0) biasg[b * Kn + row] = -0.5f * ssq * SC2;
    } else {
        const int blk = blockIdx.x - 512;
        const int b  = blk >> 5;
        const int k0 = (blk & 31) * 64;
        {
            const int key = tid >> 2;
            const float* src = Vg + ((size_t)b * Kn + k0 + key) * DVn + (tid & 3) * 32;
#pragma unroll
            for (int cj = 0; cj < 4; ++cj) {
                float4 x0 = *(const float4*)(src + cj * 8);
                float4 x1 = *(const float4*)(src + cj * 8 + 4);
                bf16x8 h;
                h[0]=f2bf(x0.x); h[1]=f2bf(x0.y); h[2]=f2bf(x0.z); h[3]=f2bf(x0.w);
                h[4]=f2bf(x1.x); h[5]=f2bf(x1.y); h[6]=f2bf(x1.z); h[7]=f2bf(x1.w);
                const int ch = (tid & 3) * 4 + cj;
                const int sw = (ch + key) & 15;
                *(bf16x8*)&Ls[key * 128 + sw * 8] = h;
            }
        }
        __syncthreads();
        {
            const int v = tid >> 1;
            const int h = (tid & 1) * 32;
            short tmp[32];
#pragma unroll
            for (int j = 0; j < 32; ++j) {
                const int kk = h + j;
                const int sw = ((v >> 3) + kk) & 15;
                tmp[j] = Ls[kk * 128 + sw * 8 + (v & 7)];
            }
            short* dst = Vtb + ((size_t)b * DVn + v) * Kn + k0 + h;
#pragma unroll
            for (int j = 0; j < 4; ++j)
                *(bf16x8*)(dst + j * 8) = *(bf16x8*)(tmp + j * 8);
        }
    }
}

// epilogue helpers with LITERAL accumulator indices (no runtime Oacc[] index)
#define DUMP_ACC(ACC, DST)                                            \
    {                                                                 \
        _Pragma("unroll")                                             \
        for (int reg = 0; reg < 16; ++reg) {                          \
            const int row = (reg & 3) + 8 * (reg >> 2) + 4 * hi;      \
            (DST)[row * 32 + l31] = (ACC)[reg];                       \
        }                                                             \
    }
#define PSTORE_ACC(ACC, SRC, COLBASE)                                 \
    {                                                                 \
        _Pragma("unroll")                                             \
        for (int reg = 0; reg < 16; ++reg) {                          \
            const int row = (reg & 3) + 8 * (reg >> 2) + 4 * hi;      \
            const float o = (ACC)[reg] + (SRC)[row * 32 + l31];       \
            op[(size_t)(pair * 32 + row) * 128 + (COLBASE) + l31] = f2bf(o); \
        }                                                             \
    }

// ---------- main attention kernel (split-K x2) ----------
__global__ __launch_bounds__(256, 3) void attn_kernel(
    const float* __restrict__ Qg, const short* __restrict__ Kb,
    const short* __restrict__ Vtb, const float* __restrict__ biasg,
    const int* __restrict__ VL,
    short* __restrict__ Opart, float* __restrict__ Lpart,
    unsigned* __restrict__ flags, float* __restrict__ Og)
{
    // Single-buffered tiles: K at KVsh[0..8192), V at KVsh[8192..16384)
    // K tile: 64 rows x 256B, chunk XOR by (row&15)
    // V tile: 64 rows x 256B; row r holds v=2r (slots c<8) / v=2r+1 (c>=8),
    //         slot position p = c ^ (r&15)
    __shared__ __align__(16) short KVsh[2 * 64 * 128];   // 32768 B (epilogue: float slab)
    __shared__ __align__(16) float biasSh[64];           //   256 B
    __shared__ float Lsum[4][32];                        //   512 B
    __shared__ unsigned role;                            // -> ~33.6 KB total

    const int tid  = threadIdx.x;
    const int lane = tid & 63;
    const int w    = tid >> 6;    // wave 0..3
    const int pair = w >> 1;      // q-strip: rows [pair*32, pair*32+32)
    const int half = w & 1;       // key-half within the 64-key tile (wave-uniform)
    const int l31  = lane & 31;
    const int hi   = lane >> 5;

    // grid 1024: bits 0-2 = XCD, bit 3 = khalf, bits 4-9 = rest
    const int lin   = blockIdx.x;
    const int xcd   = lin & 7;
    const int g     = lin >> 3;            // 0..127
    const int b     = xcd * 2 + (g >> 6);  // 2 batches per XCD
    const int rem   = g & 63;
    const int qslot = rem >> 1;            // 0..31
    const int khalf = rem & 1;
    const int q0    = qslot * BQ;
    const int kbase = khalf * (Kn / 2);    // 16 tiles of 64 keys
    const int fidx  = ((lin >> 4) << 3) | (lin & 7);   // 0..511 per (b,qslot)

    const short* Kb_b = Kb  + (size_t)b * Kn * Dn;
    const short* Vt_b = Vtb + (size_t)b * DVn * Kn;
    const float* bias_b = biasg + b * Kn;

    short* Ksh = &KVsh[0];
    short* Vsh = &KVsh[64 * 128];

    // ---- DMA source pointers ----
    const short* ksp[4]; int kdo[4];
    const short* vsp[4]; int vdo[4];
#pragma unroll
    for (int i = 0; i < 4; ++i) {
        const int rl = w * 16 + i * 4 + (lane >> 4);       // K tile row 0..63
        const int ch = (lane & 15) ^ (rl & 15);
        ksp[i] = Kb_b + (size_t)rl * Dn + ch * 8;
        kdo[i] = (w * 16 + i * 4) * 128;
        const int rv = w * 16 + i * 4 + (lane >> 4);       // V tile row 0..63
        const int cc = (lane & 15) ^ (rv & 15);            // source chunk
        const int vv = 2 * rv + (cc >> 3);
        vsp[i] = Vt_b + (size_t)vv * Kn + (cc & 7) * 8;
        vdo[i] = (w * 16 + i * 4) * 128;
    }

    // ---- Q fragments: frag layout [n=l31][k=kt*16+hi*8+j] ----
    bf16x8 qf[8];
    {
        const float* qrow = Qg + ((size_t)b * Qn + q0 + pair * 32 + l31) * Dn;
#pragma unroll
        for (int kt = 0; kt < 8; ++kt) {
            const float* p = qrow + kt * 16 + hi * 8;
            float4 x0 = *(const float4*)(p);
            float4 x1 = *(const float4*)(p + 4);
            bf16x8 f;
            f[0]=f2bf(x0.x); f[1]=f2bf(x0.y); f[2]=f2bf(x0.z); f[3]=f2bf(x0.w);
            f[4]=f2bf(x1.x); f[5]=f2bf(x1.y); f[6]=f2bf(x1.z); f[7]=f2bf(x1.w);
            qf[kt] = f;
        }
    }
    const int vlq = VL[b * Qn + q0 + pair * 32 + l31];

    f32x16 Oacc[4];   // v = nt*32 + l31, all 128 v; keys restricted to own half
#pragma unroll
    for (int nt = 0; nt < 4; ++nt)
#pragma unroll
        for (int j = 0; j < 16; ++j) Oacc[nt][j] = 0.f;
    float psum = 0.f;

    for (int t = 0; t < 16; ++t) {
        const int k0k = kbase + t * BK;

        // ---- issue DMA for tile t into the single buffer ----
#pragma unroll
        for (int i = 0; i < 4; ++i) {
            gld16(ksp[i] + (size_t)k0k * Dn, &Ksh[kdo[i]]);
            gld16(vsp[i] + k0k,              &Vsh[vdo[i]]);
        }
        if (w == 0) gld4(bias_b + k0k + lane, &biasSh[0]);
        barrier_vm();   // tile ready (prev readers done at loop-end barrier)

        float4 bv[4];
#pragma unroll
        for (int rq = 0; rq < 4; ++rq)
            bv[rq] = *(const float4*)&biasSh[half * 32 + rq * 8 + hi * 4];

        // ---- S^T = K_half . Q^T : one 32x32 tile per wave (8 MFMA) ----
        const int kr = half * 32 + l31;
        f32x16 Sv;
#pragma unroll
        for (int j = 0; j < 16; ++j) Sv[j] = 0.f;
#pragma unroll
        for (int kt = 0; kt < 8; ++kt) {
            bf16x8 kf = *(const bf16x8*)&Ksh[kr * 128 + (((kt*2 + hi) ^ (kr & 15)) * 8)];
            Sv = __builtin_amdgcn_mfma_f32_32x32x16_bf16(kf, qf[kt], Sv, 0, 0, 0);
        }

        // ---- softmax in exp2 domain (results back into Sv) ----
#pragma unroll
        for (int rq = 0; rq < 4; ++rq) {
#pragma unroll
            for (int r = 0; r < 4; ++r) {
                const int reg = rq * 4 + r;
                const int keyg = k0k + half * 32 + rq * 8 + hi * 4 + r;
                float a = fmaf(Sv[reg], SC2, bv[rq][r]);
                a = (keyg < vlq) ? a : -200.0f;
                const float p = exp2_raw(a);
                psum += p;
                Sv[reg] = p;
            }
        }

        // ---- PV: C-layout -> A-layout via lane^32 exchange; 8 MFMA ----
#pragma unroll
        for (int kt = 0; kt < 2; ++kt) {
            unsigned kAx = __builtin_amdgcn_perm(__float_as_uint(Sv[(2*kt)*4+1]),
                                                 __float_as_uint(Sv[(2*kt)*4+0]), 0x07060302u);
            unsigned kAy = __builtin_amdgcn_perm(__float_as_uint(Sv[(2*kt)*4+3]),
                                                 __float_as_uint(Sv[(2*kt)*4+2]), 0x07060302u);
            unsigned kBx = __builtin_amdgcn_perm(__float_as_uint(Sv[(2*kt+1)*4+1]),
                                                 __float_as_uint(Sv[(2*kt+1)*4+0]), 0x07060302u);
            unsigned kBy = __builtin_amdgcn_perm(__float_as_uint(Sv[(2*kt+1)*4+3]),
                                                 __float_as_uint(Sv[(2*kt+1)*4+2]), 0x07060302u);
            const unsigned sx = hi ? kAx : kBx;
            const unsigned sy = hi ? kAy : kBy;
            const unsigned rx = __shfl_xor(sx, 32);
            const unsigned ry = __shfl_xor(sy, 32);
            uint4 au;
            au.x = hi ? rx : kAx;
            au.y = hi ? ry : kAy;
            au.z = hi ? kBx : rx;
            au.w = hi ? kBy : ry;
            const bf16x8 af = __builtin_bit_cast(bf16x8, au);
            const int kc = half * 4 + kt * 2 + hi;   // key-chunk within 64-key tile
#pragma unroll
            for (int nt = 0; nt < 4; ++nt) {
                const int v  = nt * 32 + l31;
                const int r  = v >> 1;
                const int p  = ((v & 1) * 8 + kc) ^ (r & 15);
                bf16x8 vf = *(const bf16x8*)&Vsh[r * 128 + p * 8];
                Oacc[nt] = __builtin_amdgcn_mfma_f32_32x32x16_bf16(af, vf, Oacc[nt], 0, 0, 0);
            }
        }

        barrier_lgkm();   // readers done -> next iter may overwrite the buffer
    }

    // ---- epilogue: merge key-halves within block, write partials to ws ----
    psum += __shfl_xor(psum, 32);
    if (lane < 32) Lsum[w][l31] = psum;
    __syncthreads();   // all waves done with KVsh -> reuse as float slab

    float* slab = (float*)&KVsh[0];
    {
        float* dst0 = slab + ((pair * 2 + (1 - half)) * 2 + 0) * 1024;
        float* dst1 = slab + ((pair * 2 + (1 - half)) * 2 + 1) * 1024;
        if (half == 0) {
            DUMP_ACC(Oacc[2], dst0);
            DUMP_ACC(Oacc[3], dst1);
        } else {
            DUMP_ACC(Oacc[0], dst0);
            DUMP_ACC(Oacc[1], dst1);
        }
    }
    __syncthreads();

    // per-row partial l (sum over both key-halves of this block's K-range)
    if (l31 == 0 && half == 0) {
#pragma unroll
        for (int reg = 0; reg < 16; ++reg) {
            const int ql = (reg & 3) + 8 * (reg >> 2) + 4 * hi;
            Lpart[lin * 64 + pair * 32 + ql] = Lsum[pair*2][ql] + Lsum[pair*2+1][ql];
        }
    }

    short* op = Opart + (size_t)lin * 64 * 128;
    {
        const float* src0 = slab + ((pair * 2 + half) * 2 + 0) * 1024;
        const float* src1 = slab + ((pair * 2 + half) * 2 + 1) * 1024;
        if (half == 0) {
            PSTORE_ACC(Oacc[0], src0, 0);
            PSTORE_ACC(Oacc[1], src1, 32);
        } else {
            PSTORE_ACC(Oacc[2], src0, 64);
            PSTORE_ACC(Oacc[3], src1, 96);
        }
    }

    // ---- finisher protocol: second block of the (b,qslot) pair merges ----
    __syncthreads();   // all partial stores issued before the release atomic
    if (tid == 0) {
        __threadfence();
        role = __hip_atomic_fetch_add(&flags[fidx], 1u,
                                      __ATOMIC_ACQ_REL, __HIP_MEMORY_SCOPE_AGENT);
    }
    __syncthreads();
    if (role == 1) {
        const size_t pA = (size_t)(lin & ~8) * 64 * 128;
        const size_t pB = (size_t)(lin |  8) * 64 * 128;
        const int lA = (lin & ~8) * 64;
        const int lB = (lin |  8) * 64;
        const int col   = tid & 127;
        const int rbase = (tid >> 7) * 32;
        float* og = Og + ((size_t)b * Qn + q0) * DVn;
        for (int i = 0; i < 32; ++i) {
            const int row = rbase + i;
            const float o = bf2f(Opart[pA + row * 128 + col])
                          + bf2f(Opart[pB + row * 128 + col]);
            const float l = Lpart[lA + row] + Lpart[lB + row];
            og[(size_t)row * DVn + col] = o / l;
        }
    }
}

extern "C" void kernel_launch(void* const* d_in, const int* in_sizes, int n_in,
                              void* d_out, int out_size, void* d_ws, size_t ws_size,
                              hipStream_t stream) {
    const float* Qg = (const float*)d_in[0];
    const float* Kg = (const float*)d_in[1];
    const float* Vg = (const float*)d_in[2];
    const int*   VL = (const int*)d_in[3];
    float* Og = (float*)d_out;

    // ws: Kb bf16 8MB | Vtb bf16 8MB | bias2 f32 128KB | Opart bf16 16MB |
    //     Lpart f32 256KB | flags 2KB   (total ~32.4MB)
    char* ws = (char*)d_ws;
    short*    Kb    = (short*)(ws);
    short*    Vtb   = (short*)(ws + 8388608);
    float*    bias  = (float*)(ws + 16777216);
    short*    Opart = (short*)(ws + 16908288);
    float*    Lpart = (float*)(ws + 33685504);
    unsigned* flags = (unsigned*)(ws + 33947648);

    hipMemsetAsync(flags, 0, 512 * sizeof(unsigned), stream);
    prep_kv<<<dim3(1024), dim3(256), 0, stream>>>(Kg, Vg, Kb, Vtb, bias);
    attn_kernel<<<dim3(1024), dim3(256), 0, stream>>>(Qg, Kb, Vtb, bias, VL,
                                                      Opart, Lpart, flags, Og);
}

// Round 11
// 151.753 us; speedup vs baseline: 1.9326x; 1.5768x over previous
//
#include <hip/hip_runtime.h>

// B=16, Q=2048, K=2048, D=128, DV=128
// out[b,q,:] = softmax_k((q.k - 0.5||k||^2)/sqrt(192), mask k>=valid_len) @ V
// R11 = R8 (best: attn 65us) + single-buffered V tile: LDS 66.5->50.5KB
// -> 3 blocks/CU (12 waves, was 8). V(t) issued first after the top barrier;
// PV gated by raw s_waitcnt vmcnt(5)+s_barrier (waits V only, K(t+1)+bias
// prefetch stay in flight). K stays double-buffered. Core math unchanged.

#define Bn   16
#define Qn   2048
#define Kn   2048
#define Dn   128
#define DVn  128
#define BQ   64
#define BK   64

// (1/sqrt(192)) * log2(e) : softmax computed as 2^(qk*SC2 + bias2)
#define SC2 0.10411754f

typedef short bf16x4 __attribute__((ext_vector_type(4)));
typedef short bf16x8 __attribute__((ext_vector_type(8)));
typedef float f32x16 __attribute__((ext_vector_type(16)));

__device__ __forceinline__ short f2bf(float x) {   // RNE
    union { float f; unsigned u; } v; v.f = x;
    unsigned r = (v.u + 0x7fffu + ((v.u >> 16) & 1u)) >> 16;
    return (short)r;
}

typedef const __attribute__((address_space(1))) void* gas_t;
typedef __attribute__((address_space(3))) void* las_t;
__device__ __forceinline__ void gld16(const void* g, void* l) {
    __builtin_amdgcn_global_load_lds((gas_t)g, (las_t)l, 16, 0, 0);
}
__device__ __forceinline__ void gld4(const void* g, void* l) {
    __builtin_amdgcn_global_load_lds((gas_t)g, (las_t)l, 4, 0, 0);
}
// barrier waiting only the oldest loads: vmcnt(5) leaves K(t+1)+bias in flight
__device__ __forceinline__ void barrier_vm5() {
    asm volatile("s_waitcnt vmcnt(5)" ::: "memory");
    __builtin_amdgcn_s_barrier();
    asm volatile("" ::: "memory");
}
__device__ __forceinline__ float exp2_raw(float a) {  // D = 2^S0
    float p;
    asm("v_exp_f32 %0, %1" : "=v"(p) : "v"(a));
    return p;
}

// ---------- preprocess (identical to R4..R10) ----------
__global__ __launch_bounds__(256) void prep_kv(const float* __restrict__ Kg,
                                               const float* __restrict__ Vg,
                                               short* __restrict__ Kb,
                                               short* __restrict__ Vtb,
                                               float* __restrict__ biasg) {
    __shared__ short Ls[64 * 128];
    const int tid = threadIdx.x;
    if (blockIdx.x < 512) {
        const int b  = blockIdx.x >> 5;
        const int k0 = (blockIdx.x & 31) * 64;
        const int row = k0 + (tid >> 2);
        const int c   = (tid & 3) * 32;
        const float* src = Kg + ((size_t)b * Kn + row) * Dn + c;
        short*       dst = Kb + ((size_t)b * Kn + row) * Dn + c;
        float ssq = 0.f;
#pragma unroll
        for (int j = 0; j < 4; ++j) {
            float4 x0 = *(const float4*)(src + j * 8);
            float4 x1 = *(const float4*)(src + j * 8 + 4);
            ssq += x0.x*x0.x + x0.y*x0.y + x0.z*x0.z + x0.w*x0.w
                 + x1.x*x1.x + x1.y*x1.y + x1.z*x1.z + x1.w*x1.w;
            bf16x8 h;
            h[0]=f2bf(x0.x); h[1]=f2bf(x0.y); h[2]=f2bf(x0.z); h[3]=f2bf(x0.w);
            h[4]=f2bf(x1.x); h[5]=f2bf(x1.y); h[6]=f2bf(x1.z); h[7]=f2bf(x1.w);
            *(bf16x8*)(dst + j * 8) = h;
        }
        ssq += __shfl_xor(ssq, 1);
        ssq += __shfl_xor(ssq, 2);
        if ((tid & 3) == 0) biasg[b * Kn + row] = -0.5f * ssq * SC2;
    } else {
        const int blk = blockIdx.x - 512;
        const int b  = blk >> 5;
        const int k0 = (blk & 31) * 64;
        {
            const int key = tid >> 2;
            const float* src = Vg + ((size_t)b * Kn + k0 + key) * DVn + (tid & 3) * 32;
#pragma unroll
            for (int cj = 0; cj < 4; ++cj) {
                float4 x0 = *(const float4*)(src + cj * 8);
                float4 x1 = *(const float4*)(src + cj * 8 + 4);
                bf16x8 h;
                h[0]=f2bf(x0.x); h[1]=f2bf(x0.y); h[2]=f2bf(x0.z); h[3]=f2bf(x0.w);
                h[4]=f2bf(x1.x); h[5]=f2bf(x1.y); h[6]=f2bf(x1.z); h[7]=f2bf(x1.w);
                const int ch = (tid & 3) * 4 + cj;
                const int sw = (ch + key) & 15;
                *(bf16x8*)&Ls[key * 128 + sw * 8] = h;
            }
        }
        __syncthreads();
        {
            const int v = tid >> 1;
            const int h = (tid & 1) * 32;
            short tmp[32];
#pragma unroll
            for (int j = 0; j < 32; ++j) {
                const int kk = h + j;
                const int sw = ((v >> 3) + kk) & 15;
                tmp[j] = Ls[kk * 128 + sw * 8 + (v & 7)];
            }
            short* dst = Vtb + ((size_t)b * DVn + v) * Kn + k0 + h;
#pragma unroll
            for (int j = 0; j < 4; ++j)
                *(bf16x8*)(dst + j * 8) = *(bf16x8*)(tmp + j * 8);
        }
    }
}

// epilogue helpers with LITERAL accumulator indices (no runtime Oacc[] index)
#define DUMP_ACC(ACC, DST)                                            \
    {                                                                 \
        _Pragma("unroll")                                             \
        for (int reg = 0; reg < 16; ++reg) {                          \
            const int row = (reg & 3) + 8 * (reg >> 2) + 4 * hi;      \
            (DST)[row * 32 + l31] = (ACC)[reg];                       \
        }                                                             \
    }
#define STORE_ACC(ACC, SRC, COLBASE)                                  \
    {                                                                 \
        _Pragma("unroll")                                             \
        for (int reg = 0; reg < 16; ++reg) {                          \
            const int row = (reg & 3) + 8 * (reg >> 2) + 4 * hi;      \
            const float o = (ACC)[reg] + (SRC)[row * 32 + l31];       \
            obase[(size_t)row * DVn + (COLBASE) + l31] = o * invl[reg]; \
        }                                                             \
    }

// ---------- main attention kernel ----------
__global__ __launch_bounds__(256, 2) void attn_kernel(
    const float* __restrict__ Qg, const short* __restrict__ Kb,
    const short* __restrict__ Vtb, const float* __restrict__ biasg,
    const int* __restrict__ VL, float* __restrict__ Og)
{
    // K tile (double-buffered): 64 rows x 256B, chunk XOR by (row&15)
    // V tile (single): 64 rows x 256B; row r holds v=2r (c<8) / v=2r+1 (c>=8),
    //                  slot position p = c ^ (r&15)
    __shared__ __align__(16) short Ksh[2][64 * 128];   // 32768 B (epilogue: float slab)
    __shared__ __align__(16) short Vsh[64 * 128];      // 16384 B
    __shared__ __align__(16) float biasSh[2][64];      //   512 B
    __shared__ float Lsum[4][32];                      //   512 B -> 50176 B total

    const int tid  = threadIdx.x;
    const int lane = tid & 63;
    const int w    = tid >> 6;    // wave 0..3
    const int pair = w >> 1;      // q-strip: rows [pair*32, pair*32+32)
    const int half = w & 1;       // key-half (wave-uniform)
    const int l31  = lane & 31;
    const int hi   = lane >> 5;

    const int lin  = blockIdx.x;          // 0..511 ; XCD swizzle
    const int slot = lin >> 3;
    const int b    = (lin & 7) * 2 + (slot >> 5);
    const int q0   = (slot & 31) * BQ;

    const short* Kb_b = Kb  + (size_t)b * Kn * Dn;
    const short* Vt_b = Vtb + (size_t)b * DVn * Kn;
    const float* bias_b = biasg + b * Kn;

    // ---- DMA source pointers ----
    const short* ksp[4]; int kdo[4];
    const short* vsp[4]; int vdo[4];
#pragma unroll
    for (int i = 0; i < 4; ++i) {
        const int rl = w * 16 + i * 4 + (lane >> 4);       // K tile row 0..63
        const int ch = (lane & 15) ^ (rl & 15);
        ksp[i] = Kb_b + (size_t)rl * Dn + ch * 8;
        kdo[i] = (w * 16 + i * 4) * 128;
        const int rv = w * 16 + i * 4 + (lane >> 4);       // V tile row 0..63
        const int cc = (lane & 15) ^ (rv & 15);            // source chunk
        const int vv = 2 * rv + (cc >> 3);
        vsp[i] = Vt_b + (size_t)vv * Kn + (cc & 7) * 8;
        vdo[i] = (w * 16 + i * 4) * 128;
    }

    // ---- Q fragments: frag layout [n=l31][k=kt*16+hi*8+j] ----
    bf16x8 qf[8];
    {
        const float* qrow = Qg + ((size_t)b * Qn + q0 + pair * 32 + l31) * Dn;
#pragma unroll
        for (int kt = 0; kt < 8; ++kt) {
            const float* p = qrow + kt * 16 + hi * 8;
            float4 x0 = *(const float4*)(p);
            float4 x1 = *(const float4*)(p + 4);
            bf16x8 f;
            f[0]=f2bf(x0.x); f[1]=f2bf(x0.y); f[2]=f2bf(x0.z); f[3]=f2bf(x0.w);
            f[4]=f2bf(x1.x); f[5]=f2bf(x1.y); f[6]=f2bf(x1.z); f[7]=f2bf(x1.w);
            qf[kt] = f;
        }
    }
    const int vlq = VL[b * Qn + q0 + pair * 32 + l31];

    f32x16 Oacc[4];   // v = nt*32 + l31, all 128 v; keys restricted to own half
#pragma unroll
    for (int nt = 0; nt < 4; ++nt)
#pragma unroll
        for (int j = 0; j < 16; ++j) Oacc[nt][j] = 0.f;
    float psum = 0.f;

    // prologue: K tile 0 + bias 0 (V issued per-iteration)
#pragma unroll
    for (int i = 0; i < 4; ++i) gld16(ksp[i], &Ksh[0][kdo[i]]);
    if (w == 0) gld4(bias_b + lane, &biasSh[0][0]);

    for (int k0k = 0; k0k < Kn; k0k += BK) {
        const int buf = (k0k >> 6) & 1;
        __syncthreads();   // drains vmcnt(0): K(t)+bias(t) landed; PV(t-1) done

        // ---- issue V(t) FIRST (oldest -> gated by vmcnt(5) below) ----
#pragma unroll
        for (int i = 0; i < 4; ++i)
            gld16(vsp[i] + k0k, &Vsh[vdo[i]]);
        // ---- then prefetch K(t+1) + bias(t+1) (stay in flight across PV) ----
        {
            const int nk = k0k + BK;   // t=31 reads harmless in-ws garbage
#pragma unroll
            for (int i = 0; i < 4; ++i)
                gld16(ksp[i] + (size_t)nk * Dn, &Ksh[buf ^ 1][kdo[i]]);
            if (w == 0) gld4(bias_b + nk + lane, &biasSh[buf ^ 1][0]);
        }

        float4 bv[4];
#pragma unroll
        for (int rq = 0; rq < 4; ++rq)
            bv[rq] = *(const float4*)&biasSh[buf][half * 32 + rq * 8 + hi * 4];

        // ---- S^T = K_half . Q^T : one 32x32 tile per wave (8 MFMA) ----
        const short* kbuf = Ksh[buf];
        const int kr = half * 32 + l31;
        f32x16 Sv;
#pragma unroll
        for (int j = 0; j < 16; ++j) Sv[j] = 0.f;
#pragma unroll
        for (int kt = 0; kt < 8; ++kt) {
            bf16x8 kf = *(const bf16x8*)&kbuf[kr * 128 + (((kt*2 + hi) ^ (kr & 15)) * 8)];
            Sv = __builtin_amdgcn_mfma_f32_32x32x16_bf16(kf, qf[kt], Sv, 0, 0, 0);
        }

        // ---- softmax in exp2 domain (results back into Sv) ----
#pragma unroll
        for (int rq = 0; rq < 4; ++rq) {
#pragma unroll
            for (int r = 0; r < 4; ++r) {
                const int reg = rq * 4 + r;
                const int keyg = k0k + half * 32 + rq * 8 + hi * 4 + r;
                float a = fmaf(Sv[reg], SC2, bv[rq][r]);
                a = (keyg < vlq) ? a : -200.0f;
                const float p = exp2_raw(a);
                psum += p;
                Sv[reg] = p;
            }
        }

        barrier_vm5();   // V(t) landed block-wide; K(t+1) prefetch in flight

        // ---- PV: C-layout -> A-layout via lane^32 exchange; 8 MFMA ----
#pragma unroll
        for (int kt = 0; kt < 2; ++kt) {
            unsigned kAx = __builtin_amdgcn_perm(__float_as_uint(Sv[(2*kt)*4+1]),
                                                 __float_as_uint(Sv[(2*kt)*4+0]), 0x07060302u);
            unsigned kAy = __builtin_amdgcn_perm(__float_as_uint(Sv[(2*kt)*4+3]),
                                                 __float_as_uint(Sv[(2*kt)*4+2]), 0x07060302u);
            unsigned kBx = __builtin_amdgcn_perm(__float_as_uint(Sv[(2*kt+1)*4+1]),
                                                 __float_as_uint(Sv[(2*kt+1)*4+0]), 0x07060302u);
            unsigned kBy = __builtin_amdgcn_perm(__float_as_uint(Sv[(2*kt+1)*4+3]),
                                                 __float_as_uint(Sv[(2*kt+1)*4+2]), 0x07060302u);
            const unsigned sx = hi ? kAx : kBx;
            const unsigned sy = hi ? kAy : kBy;
            const unsigned rx = __shfl_xor(sx, 32);
            const unsigned ry = __shfl_xor(sy, 32);
            uint4 au;
            au.x = hi ? rx : kAx;
            au.y = hi ? ry : kAy;
            au.z = hi ? kBx : rx;
            au.w = hi ? kBy : ry;
            const bf16x8 af = __builtin_bit_cast(bf16x8, au);
            const int kc = half * 4 + kt * 2 + hi;   // key-chunk within 64-key tile
#pragma unroll
            for (int nt = 0; nt < 4; ++nt) {
                const int v  = nt * 32 + l31;
                const int r  = v >> 1;
                const int p  = ((v & 1) * 8 + kc) ^ (r & 15);
                bf16x8 vf = *(const bf16x8*)&Vsh[r * 128 + p * 8];
                Oacc[nt] = __builtin_amdgcn_mfma_f32_32x32x16_bf16(af, vf, Oacc[nt], 0, 0, 0);
            }
        }
    }

    // ---- epilogue: combine key-halves across wave pairs via LDS ----
    psum += __shfl_xor(psum, 32);
    if (lane < 32) Lsum[w][l31] = psum;
    __syncthreads();   // drains trailing prefetch; all waves done with tiles

    float* slab = (float*)&Ksh[0][0];
    {
        float* dst0 = slab + ((pair * 2 + (1 - half)) * 2 + 0) * 1024;
        float* dst1 = slab + ((pair * 2 + (1 - half)) * 2 + 1) * 1024;
        if (half == 0) {
            DUMP_ACC(Oacc[2], dst0);
            DUMP_ACC(Oacc[3], dst1);
        } else {
            DUMP_ACC(Oacc[0], dst0);
            DUMP_ACC(Oacc[1], dst1);
        }
    }
    __syncthreads();

    float invl[16];
#pragma unroll
    for (int rq = 0; rq < 4; ++rq)
#pragma unroll
        for (int r = 0; r < 4; ++r) {
            const int ql = r + 8 * rq + 4 * hi;
            invl[rq*4+r] = 1.f / (Lsum[pair*2][ql] + Lsum[pair*2+1][ql]);
        }
    float* obase = Og + ((size_t)b * Qn + q0 + pair * 32) * DVn;
    {
        const float* src0 = slab + ((pair * 2 + half) * 2 + 0) * 1024;
        const float* src1 = slab + ((pair * 2 + half) * 2 + 1) * 1024;
        if (half == 0) {
            STORE_ACC(Oacc[0], src0, 0);
            STORE_ACC(Oacc[1], src1, 32);
        } else {
            STORE_ACC(Oacc[2], src0, 64);
            STORE_ACC(Oacc[3], src1, 96);
        }
    }
}

extern "C" void kernel_launch(void* const* d_in, const int* in_sizes, int n_in,
                              void* d_out, int out_size, void* d_ws, size_t ws_size,
                              hipStream_t stream) {
    const float* Qg = (const float*)d_in[0];
    const float* Kg = (const float*)d_in[1];
    const float* Vg = (const float*)d_in[2];
    const int*   VL = (const int*)d_in[3];
    float* Og = (float*)d_out;

    // ws: Kb bf16 (8MB) | Vtb bf16 (8MB) | bias2 f32 (128KB)
    char* ws = (char*)d_ws;
    short* Kb   = (short*)(ws);
    short* Vtb  = (short*)(ws + (size_t)Bn * Kn * Dn * 2);
    float* bias = (float*)(ws + (size_t)Bn * Kn * Dn * 4);

    prep_kv<<<dim3(1024), dim3(256), 0, stream>>>(Kg, Vg, Kb, Vtb, bias);
    attn_kernel<<<dim3(512), dim3(256), 0, stream>>>(Qg, Kb, Vtb, bias, VL, Og);
}